// Round 25
// baseline (66.726 us; speedup 1.0000x reference)
//
#include <hip/hip_runtime.h>
#include <math.h>

#define NUM_E 6
#define DIM 1024
#define HID 256
#define NTOK 32768
#define NPB 4096   // tokens per batch (N)
#define TTYPE_UNKNOWN 5
#define ONE_MINUS_ALPHA 0.775f
#define FLOOR_TERM 0.0375f     // alpha * (1/E)
#define GRP 8                  // tokens per MLP block (683 working blocks; W1-reuse lever)
#define KSPLIT 8               // K segments (tid>>6), each 128 wide
#define KSPAN 128
#define CPT 4                  // consecutive columns per thread (float4 W1 loads)

// Closed-form top1 + hard-cap + combine for a probs vector of 6.
__device__ __forceinline__ void finalize_and_write(const float probs[NUM_E], float cap,
                                                   float* __restrict__ disp_out,
                                                   float* __restrict__ comb_out) {
    float v = probs[0];
    int bi = 0;
#pragma unroll
    for (int e = 1; e < NUM_E; ++e) {
        if (probs[e] > v) { v = probs[e]; bi = e; }
    }
    float excess = fmaxf(v - cap, 0.0f);
    float capped = v - excess;                 // min(v, cap)
    float hr_idx = fmaxf(cap - capped, 0.0f);
    float hsum = fmaxf(hr_idx + 5.0f * cap, 1e-8f);
    float disp[NUM_E];
    float other = excess * cap / hsum;
#pragma unroll
    for (int e = 0; e < NUM_E; ++e) disp[e] = other;
    disp[bi] = capped + excess * hr_idx / hsum;
    float s = 0.0f;
#pragma unroll
    for (int e = 0; e < NUM_E; ++e) s += disp[e];
    float inv = 1.0f / (s + 1e-8f);
#pragma unroll
    for (int e = 0; e < NUM_E; ++e) {
        disp_out[e] = disp[e];
        comb_out[e] = disp[e] * inv;
    }
}

// Known tokens -> final output directly; unknown -> compacted list.
__launch_bounds__(256)
__global__ void classify_kernel(const int* __restrict__ ttypes,
                                const int* __restrict__ tarr,
                                const float* __restrict__ base,
                                float* __restrict__ out,
                                int* __restrict__ cnt,
                                int* __restrict__ list) {
    int i = blockIdx.x * blockDim.x + threadIdx.x;
    if (i >= NTOK) return;
    int ty = ttypes[i];
    if (ty == TTYPE_UNKNOWN) {
        int pos = atomicAdd(cnt, 1);
        list[pos] = i;
        return;
    }
    int b = i / NPB;
    float tnorm = (float)tarr[b] / 1000.0f;
    float cap = 0.5f + 1.1f * tnorm;
    float probs[NUM_E];
#pragma unroll
    for (int e = 0; e < NUM_E; ++e)
        probs[e] = ONE_MINUS_ALPHA * base[ty * NUM_E + e] + FLOOR_TERM;
    finalize_and_write(probs, cap,
                       out + (size_t)i * NUM_E,
                       out + (size_t)NTOK * NUM_E + (size_t)i * NUM_E);
}

// Fused MLP gate, 512 threads = 8 waves, GRP=8 tokens staged once in 32 KB LDS.
// R24 proven shape (CPT=4, paired-token epilogue) with #pragma unroll 4:
// 4 independent iterations in the scheduler window (8 VMEM + 16 LDS loads in
// flight over 512 FMAs). Transient regs ~60 -- at the allocator's comfort
// edge; spill check = WRITE_SIZE.
__launch_bounds__(512)
__global__ void mlp_kernel(const float* __restrict__ tokens,
                           const int* __restrict__ tarr,
                           const float* __restrict__ W1,
                           const float* __restrict__ b1,
                           const float* __restrict__ W2,
                           const float* __restrict__ b2,
                           float* __restrict__ out,
                           const int* __restrict__ cnt,
                           const int* __restrict__ list) {
    __shared__ float smem[GRP * DIM];    // 32 KB: xs in K-loop; hp+hs after
    __shared__ float w2s[HID * NUM_E];   // 6 KB
    __shared__ float ls[GRP][NUM_E];

    int count = cnt[0];
    int start = blockIdx.x * GRP;
    if (start >= count) return;
    int tid = threadIdx.x;

    float (*xs)[DIM] = (float (*)[DIM])smem;

    // Stage 8 token rows: 2048 float4 slots, 512 threads -> 4 each, coalesced.
    {
        int slot = tid & 255;            // float4 slot within a row
        int rr = tid >> 8;               // 0..1
#pragma unroll
        for (int p = 0; p < 4; ++p) {
            int r = rr * 4 + p;
            int idx = start + r;
            if (idx > count - 1) idx = count - 1;   // dup tail -> idempotent writes
            int tok = list[idx];
            const float4* src = reinterpret_cast<const float4*>(tokens + (size_t)tok * DIM);
            reinterpret_cast<float4*>(xs[r])[slot] = src[slot];
        }
    }
    for (int kk = tid; kk < HID * NUM_E; kk += 512) w2s[kk] = W2[kk];
    __syncthreads();

    int cg = tid & 63;                   // column group: cols [4cg, 4cg+4)
    int ks = tid >> 6;                   // 0..7
    int kbase = ks * KSPAN;
    int colbase = cg * CPT;

    float acc[GRP][CPT];
#pragma unroll
    for (int r = 0; r < GRP; ++r)
#pragma unroll
        for (int c = 0; c < CPT; ++c) acc[r][c] = 0.0f;

    const float* w1p = W1 + (size_t)kbase * HID + colbase;
    const float* xbase = &xs[0][kbase];  // + r*DIM + k at imm offsets (r static)

#pragma unroll 4
    for (int k = 0; k < KSPAN; k += 4) {
        // 4 coalesced float4 W1 loads (4 k-rows x one 4-col block)
        float4 w[4];
        const float* wp = w1p + (size_t)k * HID;
#pragma unroll
        for (int kk = 0; kk < 4; ++kk)
            w[kk] = *reinterpret_cast<const float4*>(wp + kk * HID);
        // 8 broadcast b128 x-reads (imm offsets), 128 FMA
#pragma unroll
        for (int r = 0; r < GRP; ++r) {
            float4 xq = *reinterpret_cast<const float4*>(xbase + r * DIM + k);
            acc[r][0] = fmaf(xq.x, w[0].x, acc[r][0]);
            acc[r][1] = fmaf(xq.x, w[0].y, acc[r][1]);
            acc[r][2] = fmaf(xq.x, w[0].z, acc[r][2]);
            acc[r][3] = fmaf(xq.x, w[0].w, acc[r][3]);
            acc[r][0] = fmaf(xq.y, w[1].x, acc[r][0]);
            acc[r][1] = fmaf(xq.y, w[1].y, acc[r][1]);
            acc[r][2] = fmaf(xq.y, w[1].z, acc[r][2]);
            acc[r][3] = fmaf(xq.y, w[1].w, acc[r][3]);
            acc[r][0] = fmaf(xq.z, w[2].x, acc[r][0]);
            acc[r][1] = fmaf(xq.z, w[2].y, acc[r][1]);
            acc[r][2] = fmaf(xq.z, w[2].z, acc[r][2]);
            acc[r][3] = fmaf(xq.z, w[2].w, acc[r][3]);
            acc[r][0] = fmaf(xq.w, w[3].x, acc[r][0]);
            acc[r][1] = fmaf(xq.w, w[3].y, acc[r][1]);
            acc[r][2] = fmaf(xq.w, w[3].z, acc[r][2]);
            acc[r][3] = fmaf(xq.w, w[3].w, acc[r][3]);
        }
    }
    __syncthreads();   // all xs reads done; re-purpose smem

    // aliased region (floats): hp[8][2][256] @0 (16 KB), hs[8][257] @4096
    float (*hp)[2][HID] = (float (*)[2][HID])smem;
    float (*hs)[HID + 1] = (float (*)[HID + 1])(smem + 4096);

    const float kc = 0.70710678118654752f;
#pragma unroll 1
    for (int r0 = 0; r0 < GRP; r0 += 2) {
        // write two tokens' partials: hp[ks][0/1][colbase..+3] (two b128)
#pragma unroll
        for (int c = 0; c < CPT; ++c) hp[ks][0][colbase + c] = acc[r0][c];
#pragma unroll
        for (int c = 0; c < CPT; ++c) hp[ks][1][colbase + c] = acc[r0 + 1][c];
        __syncthreads();
        {
            int tr = tid >> 8;           // 0..1 (token within pair)
            int col = tid & 255;
            float s = hp[0][tr][col];
#pragma unroll
            for (int q = 1; q < KSPLIT; ++q) s += hp[q][tr][col];
            float pre = s + b1[col];
            hs[r0 + tr][col] = 0.5f * pre * (1.0f + erff(pre * kc));
        }
        __syncthreads();
    }

    // Layer 2: 48 threads, one (token, expert) dot each
    if (tid < GRP * NUM_E) {
        int r = tid / NUM_E, e = tid % NUM_E;
        float s = 0.0f;
        for (int j = 0; j < HID; ++j) s = fmaf(hs[r][j], w2s[j * NUM_E + e], s);
        ls[r][e] = (s + b2[e]) / 0.1f;   // temperature
    }
    __syncthreads();

    // Finalize per token
    if (tid < GRP && start + tid < count) {
        int tokidx = list[start + tid];
        int b = tokidx / NPB;
        float tnorm = (float)tarr[b] / 1000.0f;
        float cap = 0.5f + 1.1f * tnorm;
        float probs[NUM_E];
#pragma unroll
        for (int e = 0; e < NUM_E; ++e)
            probs[e] = ONE_MINUS_ALPHA * ls[tid][e] + FLOOR_TERM;
        finalize_and_write(probs, cap,
                           out + (size_t)tokidx * NUM_E,
                           out + (size_t)NTOK * NUM_E + (size_t)tokidx * NUM_E);
    }
}

extern "C" void kernel_launch(void* const* d_in, const int* in_sizes, int n_in,
                              void* d_out, int out_size, void* d_ws, size_t ws_size,
                              hipStream_t stream) {
    const float* tokens = (const float*)d_in[0];
    const int*   ttypes = (const int*)d_in[1];
    const int*   tarr   = (const int*)d_in[2];
    const float* W1     = (const float*)d_in[3];
    const float* b1     = (const float*)d_in[4];
    const float* W2     = (const float*)d_in[5];
    const float* b2     = (const float*)d_in[6];
    const float* base   = (const float*)d_in[7];
    float* out = (float*)d_out;

    int* cnt  = (int*)d_ws;
    int* list = (int*)d_ws + 64;   // 256 B offset; list worst case 128 KB

    hipMemsetAsync(cnt, 0, sizeof(int), stream);
    classify_kernel<<<NTOK / 256, 256, 0, stream>>>(ttypes, tarr, base, out, cnt, list);
    mlp_kernel<<<NTOK / GRP, 512, 0, stream>>>(tokens, tarr, W1, b1, W2, b2,
                                               out, cnt, list);
}

// Round 26
// 66.187 us; speedup vs baseline: 1.0081x; 1.0081x over previous
//
#include <hip/hip_runtime.h>
#include <math.h>

#define NUM_E 6
#define DIM 1024
#define HID 256
#define NTOK 32768
#define NPB 4096   // tokens per batch (N)
#define TTYPE_UNKNOWN 5
#define ONE_MINUS_ALPHA 0.775f
#define FLOOR_TERM 0.0375f     // alpha * (1/E)
#define GRP 8                  // tokens per MLP block (683 working blocks; W1-reuse lever)
#define KSPLIT 8               // K segments (tid>>6), each 128 wide
#define KSPAN 128
#define CPT 4                  // consecutive columns per thread (float4 W1 loads)

// Closed-form top1 + hard-cap + combine for a probs vector of 6.
__device__ __forceinline__ void finalize_and_write(const float probs[NUM_E], float cap,
                                                   float* __restrict__ disp_out,
                                                   float* __restrict__ comb_out) {
    float v = probs[0];
    int bi = 0;
#pragma unroll
    for (int e = 1; e < NUM_E; ++e) {
        if (probs[e] > v) { v = probs[e]; bi = e; }
    }
    float excess = fmaxf(v - cap, 0.0f);
    float capped = v - excess;                 // min(v, cap)
    float hr_idx = fmaxf(cap - capped, 0.0f);
    float hsum = fmaxf(hr_idx + 5.0f * cap, 1e-8f);
    float disp[NUM_E];
    float other = excess * cap / hsum;
#pragma unroll
    for (int e = 0; e < NUM_E; ++e) disp[e] = other;
    disp[bi] = capped + excess * hr_idx / hsum;
    float s = 0.0f;
#pragma unroll
    for (int e = 0; e < NUM_E; ++e) s += disp[e];
    float inv = 1.0f / (s + 1e-8f);
#pragma unroll
    for (int e = 0; e < NUM_E; ++e) {
        disp_out[e] = disp[e];
        comb_out[e] = disp[e] * inv;
    }
}

// Known tokens -> final output directly; unknown -> compacted list.
__launch_bounds__(256)
__global__ void classify_kernel(const int* __restrict__ ttypes,
                                const int* __restrict__ tarr,
                                const float* __restrict__ base,
                                float* __restrict__ out,
                                int* __restrict__ cnt,
                                int* __restrict__ list) {
    int i = blockIdx.x * blockDim.x + threadIdx.x;
    if (i >= NTOK) return;
    int ty = ttypes[i];
    if (ty == TTYPE_UNKNOWN) {
        int pos = atomicAdd(cnt, 1);
        list[pos] = i;
        return;
    }
    int b = i / NPB;
    float tnorm = (float)tarr[b] / 1000.0f;
    float cap = 0.5f + 1.1f * tnorm;
    float probs[NUM_E];
#pragma unroll
    for (int e = 0; e < NUM_E; ++e)
        probs[e] = ONE_MINUS_ALPHA * base[ty * NUM_E + e] + FLOOR_TERM;
    finalize_and_write(probs, cap,
                       out + (size_t)i * NUM_E,
                       out + (size_t)NTOK * NUM_E + (size_t)i * NUM_E);
}

// Fused MLP gate, 512 threads = 8 waves, GRP=8 tokens staged once in 32 KB LDS.
// Terminal configuration (R24): CPT=4 consecutive cols/thread (float4 W1
// loads), KSPLIT=8, unroll 2, paired-token epilogue (8 barriers). 44 VGPR,
// no spill, ~2.67 blocks/CU. Measured 66.0 us total, absmax 0.0.
__launch_bounds__(512)
__global__ void mlp_kernel(const float* __restrict__ tokens,
                           const int* __restrict__ tarr,
                           const float* __restrict__ W1,
                           const float* __restrict__ b1,
                           const float* __restrict__ W2,
                           const float* __restrict__ b2,
                           float* __restrict__ out,
                           const int* __restrict__ cnt,
                           const int* __restrict__ list) {
    __shared__ float smem[GRP * DIM];    // 32 KB: xs in K-loop; hp+hs after
    __shared__ float w2s[HID * NUM_E];   // 6 KB
    __shared__ float ls[GRP][NUM_E];

    int count = cnt[0];
    int start = blockIdx.x * GRP;
    if (start >= count) return;
    int tid = threadIdx.x;

    float (*xs)[DIM] = (float (*)[DIM])smem;

    // Stage 8 token rows: 2048 float4 slots, 512 threads -> 4 each, coalesced.
    {
        int slot = tid & 255;            // float4 slot within a row
        int rr = tid >> 8;               // 0..1
#pragma unroll
        for (int p = 0; p < 4; ++p) {
            int r = rr * 4 + p;
            int idx = start + r;
            if (idx > count - 1) idx = count - 1;   // dup tail -> idempotent writes
            int tok = list[idx];
            const float4* src = reinterpret_cast<const float4*>(tokens + (size_t)tok * DIM);
            reinterpret_cast<float4*>(xs[r])[slot] = src[slot];
        }
    }
    for (int kk = tid; kk < HID * NUM_E; kk += 512) w2s[kk] = W2[kk];
    __syncthreads();

    int cg = tid & 63;                   // column group: cols [4cg, 4cg+4)
    int ks = tid >> 6;                   // 0..7
    int kbase = ks * KSPAN;
    int colbase = cg * CPT;

    float acc[GRP][CPT];
#pragma unroll
    for (int r = 0; r < GRP; ++r)
#pragma unroll
        for (int c = 0; c < CPT; ++c) acc[r][c] = 0.0f;

    const float* w1p = W1 + (size_t)kbase * HID + colbase;
    const float* xbase = &xs[0][kbase];  // + r*DIM + k at imm offsets (r static)

#pragma unroll 2
    for (int k = 0; k < KSPAN; k += 4) {
        // 4 coalesced float4 W1 loads (4 k-rows x one 4-col block)
        float4 w[4];
        const float* wp = w1p + (size_t)k * HID;
#pragma unroll
        for (int kk = 0; kk < 4; ++kk)
            w[kk] = *reinterpret_cast<const float4*>(wp + kk * HID);
        // 8 broadcast b128 x-reads (imm offsets), 128 FMA
#pragma unroll
        for (int r = 0; r < GRP; ++r) {
            float4 xq = *reinterpret_cast<const float4*>(xbase + r * DIM + k);
            acc[r][0] = fmaf(xq.x, w[0].x, acc[r][0]);
            acc[r][1] = fmaf(xq.x, w[0].y, acc[r][1]);
            acc[r][2] = fmaf(xq.x, w[0].z, acc[r][2]);
            acc[r][3] = fmaf(xq.x, w[0].w, acc[r][3]);
            acc[r][0] = fmaf(xq.y, w[1].x, acc[r][0]);
            acc[r][1] = fmaf(xq.y, w[1].y, acc[r][1]);
            acc[r][2] = fmaf(xq.y, w[1].z, acc[r][2]);
            acc[r][3] = fmaf(xq.y, w[1].w, acc[r][3]);
            acc[r][0] = fmaf(xq.z, w[2].x, acc[r][0]);
            acc[r][1] = fmaf(xq.z, w[2].y, acc[r][1]);
            acc[r][2] = fmaf(xq.z, w[2].z, acc[r][2]);
            acc[r][3] = fmaf(xq.z, w[2].w, acc[r][3]);
            acc[r][0] = fmaf(xq.w, w[3].x, acc[r][0]);
            acc[r][1] = fmaf(xq.w, w[3].y, acc[r][1]);
            acc[r][2] = fmaf(xq.w, w[3].z, acc[r][2]);
            acc[r][3] = fmaf(xq.w, w[3].w, acc[r][3]);
        }
    }
    __syncthreads();   // all xs reads done; re-purpose smem

    // aliased region (floats): hp[8][2][256] @0 (16 KB), hs[8][257] @4096
    float (*hp)[2][HID] = (float (*)[2][HID])smem;
    float (*hs)[HID + 1] = (float (*)[HID + 1])(smem + 4096);

    const float kc = 0.70710678118654752f;
#pragma unroll 1
    for (int r0 = 0; r0 < GRP; r0 += 2) {
        // write two tokens' partials: hp[ks][0/1][colbase..+3] (two b128)
#pragma unroll
        for (int c = 0; c < CPT; ++c) hp[ks][0][colbase + c] = acc[r0][c];
#pragma unroll
        for (int c = 0; c < CPT; ++c) hp[ks][1][colbase + c] = acc[r0 + 1][c];
        __syncthreads();
        {
            int tr = tid >> 8;           // 0..1 (token within pair)
            int col = tid & 255;
            float s = hp[0][tr][col];
#pragma unroll
            for (int q = 1; q < KSPLIT; ++q) s += hp[q][tr][col];
            float pre = s + b1[col];
            hs[r0 + tr][col] = 0.5f * pre * (1.0f + erff(pre * kc));
        }
        __syncthreads();
    }

    // Layer 2: 48 threads, one (token, expert) dot each
    if (tid < GRP * NUM_E) {
        int r = tid / NUM_E, e = tid % NUM_E;
        float s = 0.0f;
        for (int j = 0; j < HID; ++j) s = fmaf(hs[r][j], w2s[j * NUM_E + e], s);
        ls[r][e] = (s + b2[e]) / 0.1f;   // temperature
    }
    __syncthreads();

    // Finalize per token
    if (tid < GRP && start + tid < count) {
        int tokidx = list[start + tid];
        int b = tokidx / NPB;
        float tnorm = (float)tarr[b] / 1000.0f;
        float cap = 0.5f + 1.1f * tnorm;
        float probs[NUM_E];
#pragma unroll
        for (int e = 0; e < NUM_E; ++e)
            probs[e] = ONE_MINUS_ALPHA * ls[tid][e] + FLOOR_TERM;
        finalize_and_write(probs, cap,
                           out + (size_t)tokidx * NUM_E,
                           out + (size_t)NTOK * NUM_E + (size_t)tokidx * NUM_E);
    }
}

extern "C" void kernel_launch(void* const* d_in, const int* in_sizes, int n_in,
                              void* d_out, int out_size, void* d_ws, size_t ws_size,
                              hipStream_t stream) {
    const float* tokens = (const float*)d_in[0];
    const int*   ttypes = (const int*)d_in[1];
    const int*   tarr   = (const int*)d_in[2];
    const float* W1     = (const float*)d_in[3];
    const float* b1     = (const float*)d_in[4];
    const float* W2     = (const float*)d_in[5];
    const float* b2     = (const float*)d_in[6];
    const float* base   = (const float*)d_in[7];
    float* out = (float*)d_out;

    int* cnt  = (int*)d_ws;
    int* list = (int*)d_ws + 64;   // 256 B offset; list worst case 128 KB

    hipMemsetAsync(cnt, 0, sizeof(int), stream);
    classify_kernel<<<NTOK / 256, 256, 0, stream>>>(ttypes, tarr, base, out, cnt, list);
    mlp_kernel<<<NTOK / GRP, 512, 0, stream>>>(tokens, tarr, W1, b1, W2, b2,
                                               out, cnt, list);
}